// Round 18
// baseline (334.263 us; speedup 1.0000x reference)
//
#include <hip/hip_runtime.h>
#include <hip/hip_bf16.h>

// ChebyKAN: y[b,o] = sum_{i,d} T_d(tanh(x[b,i])) * W[i,o,d]
// GEMM M=16384, N=1024, K=9216 with generated A (packed-fp16 Chebyshev recurrence).
// R14: LDS 144KB -> 80KB ring-of-10 (stage 1 buf/phase, consumed 9 phases later)
//      => 2 blocks/CU co-resident (was 1; barriers/LDS latency now hidden by the
//      other block). R13 fine-phase schedule otherwise unchanged; waits re-derived:
//      phase0 vmcnt(7), phases1-7 vmcnt(11), phase8 no barrier, chunk31 vmcnt(0).

#define WSCALE 4096.0f
#define INV_WSCALE (1.0f/4096.0f)

typedef _Float16 f16;
typedef __fp16   hf2  __attribute__((ext_vector_type(2)));
typedef _Float16 f16x8 __attribute__((ext_vector_type(8)));
typedef float    f32x4 __attribute__((ext_vector_type(4)));
typedef float    f32x16 __attribute__((ext_vector_type(16)));

union F16x8u { hf2 h2[4]; f16x8 v8; };

// ---- kernel 1: repack cc [I][O][9] f32 -> wt (R5 conflict-free layout)
__global__ __launch_bounds__(256) void wt_transform(const float* __restrict__ cc,
                                                    f16* __restrict__ wt) {
  int t    = blockIdx.x * 256 + threadIdx.x;   // 294912 threads
  int j4   = t & 127;
  int grp  = t >> 7;
  int ncol = grp & 7;
  int rest = grp >> 3;
  int ic   = rest & 31;
  int d    = rest >> 5;                        // 0..8
  int u    = j4 >> 5;
  int h    = (j4 >> 4) & 1;
  int r    = j4 & 15;
  int rk   = (r >> 1) & 3;
  size_t base = (size_t)(d * 32 + ic) * 32768 + (size_t)ncol * 4096 + (size_t)j4 * 32;
#pragma unroll
  for (int v = 0; v < 4; ++v) {
    int tt = v ^ rk;
    int q  = tt & 1, kl = tt >> 1;
    int o  = ncol * 128 + u * 32 + q * 16 + r;
    int ib = ic * 32 + h * 16 + kl * 8;
    f16x8 val;
#pragma unroll
    for (int e = 0; e < 8; ++e)
      val[e] = (f16)(cc[((size_t)(ib + e) * 1024 + o) * 9 + d] * WSCALE);
    *(f16x8*)(wt + base + v * 8) = val;
  }
}

// ---- kernel 1b: t2 = 2*tanh(x) as f16
__global__ __launch_bounds__(256) void t2_transform(const float* __restrict__ x,
                                                    f16* __restrict__ t2) {
  size_t gid = (size_t)blockIdx.x * 256 + threadIdx.x;   // 2,097,152 threads
  const float* p = x + gid * 8;
  f32x4 a = *(const f32x4*)p;
  f32x4 b = *(const f32x4*)(p + 4);
  float tf[8];
#pragma unroll
  for (int e = 0; e < 8; ++e) {
    float xx = (e < 4) ? a[e] : b[e - 4];
    tf[e] = 1.f - 2.f * __builtin_amdgcn_rcpf(__expf(2.f * xx) + 1.f);
  }
  F16x8u u;
#pragma unroll
  for (int q = 0; q < 4; ++q)
    u.h2[q] = __builtin_amdgcn_cvt_pkrtz(tf[2 * q], tf[2 * q + 1]);
  f16x8 v = u.v8 + u.v8;
  *(f16x8*)(t2 + gid * 8) = v;
}

// ---- kernel 2: fused basis-gen + GEMM, 256x128 tile, 8 waves of 64m x 64n
__global__ __launch_bounds__(512, 2) void cheby_gemm(const f16* __restrict__ t2g,
                                                     const f16* __restrict__ wt,
                                                     float* __restrict__ out) {
  __shared__ f16 bbuf[10][4096];              // ring of 10 x 8KB = 80KB -> 2 blocks/CU

  const int tid  = threadIdx.x;
  const int wid  = tid >> 6;
  const int lane = tid & 63;
  const int lr   = lane & 31;
  const int lh   = lane >> 5;
  const int wm   = wid >> 1;
  const int wn   = wid & 1;
  const int mrow = blockIdx.x >> 3;
  const int ncol = blockIdx.x & 7;
  const int m0   = mrow * 256 + wm * 64;
  const int n0   = ncol * 128 + wn * 64;
  const int rbase = wn * 2048 + ((lane & 15) * 4 + ((lane >> 4) ^ ((lane >> 1) & 3))) * 8;

  auto stage = [&](int cn, int dn, int slot) {
    const f16* src = wt + (size_t)(dn * 32 + cn) * 32768 + (size_t)ncol * 4096;
    __builtin_amdgcn_global_load_lds(
        (const __attribute__((address_space(1))) unsigned*)(src + tid * 8),
        (__attribute__((address_space(3))) unsigned*)(&bbuf[slot][wid * 512]),
        16, 0, 0);
  };

  f32x16 acc[2][2];
#pragma unroll
  for (int a = 0; a < 2; ++a)
#pragma unroll
    for (int b = 0; b < 2; ++b)
#pragma unroll
      for (int j = 0; j < 16; ++j) acc[a][b][j] = 0.f;

  const f16x8 ones  = {(f16)1,(f16)1,(f16)1,(f16)1,(f16)1,(f16)1,(f16)1,(f16)1};
  const f16x8 half8 = {(f16)0.5f,(f16)0.5f,(f16)0.5f,(f16)0.5f,
                       (f16)0.5f,(f16)0.5f,(f16)0.5f,(f16)0.5f};
  f16x8 t2v[2][2], t2n[2][2];

  auto loadx = [&](int cn) {   // 4 VMEM f16x8 -> t2n
#pragma unroll
    for (int mb = 0; mb < 2; ++mb)
#pragma unroll
      for (int h = 0; h < 2; ++h)
        t2n[mb][h] = *(const f16x8*)(t2g + (size_t)(m0 + mb * 32 + lr) * 1024
                                         + cn * 32 + h * 16 + lh * 8);
  };

#define REC(NEW, S1, S2)                                                       \
  _Pragma("unroll") for (int mb = 0; mb < 2; ++mb)                             \
    _Pragma("unroll") for (int h = 0; h < 2; ++h)                              \
      NEW[mb][h] = __builtin_elementwise_fma(t2v[mb][h], S1[mb][h], -S2[mb][h]);

#define LOADB(BD, SLOT)                                                        \
  {                                                                            \
    const f16* bb = &bbuf[(SLOT)][0] + rbase;                                  \
    BD[0][0] = *(const f16x8*)&bb[0];    BD[0][1] = *(const f16x8*)&bb[512];   \
    BD[1][0] = *(const f16x8*)&bb[1024]; BD[1][1] = *(const f16x8*)&bb[1536];  \
  }

#define MFMA8(AF, BD)                                                          \
  {                                                                            \
    __builtin_amdgcn_s_setprio(1);                                             \
    _Pragma("unroll") for (int nb = 0; nb < 2; ++nb)                           \
      _Pragma("unroll") for (int mb = 0; mb < 2; ++mb) {                       \
        acc[mb][nb] = __builtin_amdgcn_mfma_f32_32x32x16_f16(AF[mb][0], BD[nb][0], \
                                                             acc[mb][nb], 0, 0, 0); \
        acc[mb][nb] = __builtin_amdgcn_mfma_f32_32x32x16_f16(AF[mb][1], BD[nb][1], \
                                                             acc[mb][nb], 0, 0, 0); \
      }                                                                        \
    __builtin_amdgcn_s_setprio(0);                                             \
  }

#define VMB(N)                                                                 \
  asm volatile("s_waitcnt vmcnt(" #N ")" ::: "memory");                        \
  __builtin_amdgcn_s_barrier();

  // prologue: stage steps 0..8 -> slots 0..8, loadx(0)
#pragma unroll
  for (int d = 0; d < 9; ++d) stage(0, d, d);
  loadx(0);

  f16x8 onesA[2][2];
#pragma unroll
  for (int mb = 0; mb < 2; ++mb)
#pragma unroll
    for (int h = 0; h < 2; ++h) onesA[mb][h] = ones;

  f16x8 bfA[2][2], bfB[2][2];
  f16x8 A1[2][2], A2[2][2], A3[2][2], A4[2][2], A5[2][2], A6[2][2], A7[2][2], A8[2][2];

  int s0 = 0;                                  // slot of step 9c (ring base)
  for (int c = 0; c < 31; ++c) {
    // slots q0..q9 = (s0+k) % 10
    const int q0 = s0;
    const int q1 = (s0 + 1 > 9) ? s0 - 9 : s0 + 1;
    const int q2 = (s0 + 2 > 9) ? s0 - 8 : s0 + 2;
    const int q3 = (s0 + 3 > 9) ? s0 - 7 : s0 + 3;
    const int q4 = (s0 + 4 > 9) ? s0 - 6 : s0 + 4;
    const int q5 = (s0 + 5 > 9) ? s0 - 5 : s0 + 5;
    const int q6 = (s0 + 6 > 9) ? s0 - 4 : s0 + 6;
    const int q7 = (s0 + 7 > 9) ? s0 - 3 : s0 + 7;
    const int q8 = (s0 + 8 > 9) ? s0 - 2 : s0 + 8;
    const int q9 = (s0 + 9 > 9) ? s0 - 1 : s0 + 9;

    // phase 0 (deg 0): prove steps 9c, 9c+1 (and loadx(c), drained en route)
    VMB(7)
    LOADB(bfA, q0)
#pragma unroll
    for (int mb = 0; mb < 2; ++mb)
#pragma unroll
      for (int h = 0; h < 2; ++h) {
        t2v[mb][h] = t2n[mb][h];              // adopt chunk-c t2 (before loadx!)
        A1[mb][h]  = t2v[mb][h] * half8;
      }
    stage(c + 1, 0, q9);                      // step 9c+9 -> slot (9c+9)%10
    loadx(c + 1);
    LOADB(bfB, q1)
    MFMA8(onesA, bfA)

    // phases 1..7: stage step 9c+9+d into the slot freed two phases ago
    VMB(11) stage(c + 1, 1, q0); LOADB(bfA, q2) REC(A2, A1, onesA) MFMA8(A1, bfB)
    VMB(11) stage(c + 1, 2, q1); LOADB(bfB, q3) REC(A3, A2, A1)    MFMA8(A2, bfA)
    VMB(11) stage(c + 1, 3, q2); LOADB(bfA, q4) REC(A4, A3, A2)    MFMA8(A3, bfB)
    VMB(11) stage(c + 1, 4, q3); LOADB(bfB, q5) REC(A5, A4, A3)    MFMA8(A4, bfA)
    VMB(11) stage(c + 1, 5, q4); LOADB(bfA, q6) REC(A6, A5, A4)    MFMA8(A5, bfB)
    VMB(11) stage(c + 1, 6, q5); LOADB(bfB, q7) REC(A7, A6, A5)    MFMA8(A6, bfA)
    VMB(11) stage(c + 1, 7, q6); LOADB(bfA, q8) REC(A8, A7, A6)    MFMA8(A7, bfB)

    // phase 8: deg8's B (bfA) proven at phase 7; no wait/barrier
    stage(c + 1, 8, q7);
    MFMA8(A8, bfA)

    s0 = (s0 == 0) ? 9 : s0 - 1;              // s0 += 9 mod 10
  }

  // ---- tail chunk c=31 (s0 now (9*31)%10 = 9): all staged; single full drain
  {
    const int q0 = s0;
    const int q1 = (s0 + 1 > 9) ? s0 - 9 : s0 + 1;
    const int q2 = (s0 + 2 > 9) ? s0 - 8 : s0 + 2;
    const int q3 = (s0 + 3 > 9) ? s0 - 7 : s0 + 3;
    const int q4 = (s0 + 4 > 9) ? s0 - 6 : s0 + 4;
    const int q5 = (s0 + 5 > 9) ? s0 - 5 : s0 + 5;
    const int q6 = (s0 + 6 > 9) ? s0 - 4 : s0 + 6;
    const int q7 = (s0 + 7 > 9) ? s0 - 3 : s0 + 7;
    const int q8 = (s0 + 8 > 9) ? s0 - 2 : s0 + 8;

    asm volatile("s_waitcnt vmcnt(0)" ::: "memory");
    __builtin_amdgcn_s_barrier();
    LOADB(bfA, q0)
#pragma unroll
    for (int mb = 0; mb < 2; ++mb)
#pragma unroll
      for (int h = 0; h < 2; ++h) {
        t2v[mb][h] = t2n[mb][h];
        A1[mb][h]  = t2v[mb][h] * half8;
      }
    LOADB(bfB, q1)
    MFMA8(onesA, bfA)
    LOADB(bfA, q2) REC(A2, A1, onesA) MFMA8(A1, bfB)
    LOADB(bfB, q3) REC(A3, A2, A1)    MFMA8(A2, bfA)
    LOADB(bfA, q4) REC(A4, A3, A2)    MFMA8(A3, bfB)
    LOADB(bfB, q5) REC(A5, A4, A3)    MFMA8(A4, bfA)
    LOADB(bfA, q6) REC(A6, A5, A4)    MFMA8(A5, bfB)
    LOADB(bfB, q7) REC(A7, A6, A5)    MFMA8(A6, bfA)
    LOADB(bfA, q8) REC(A8, A7, A6)    MFMA8(A7, bfB)
    MFMA8(A8, bfA)
  }
#undef REC
#undef LOADB
#undef MFMA8
#undef VMB

  // epilogue: 32x32 C/D map: col = lane&31, row = (j&3) + 8*(j>>2) + 4*(lane>>5)
#pragma unroll
  for (int mb = 0; mb < 2; ++mb)
#pragma unroll
    for (int nb = 0; nb < 2; ++nb)
#pragma unroll
      for (int j = 0; j < 16; ++j) {
        int row = m0 + mb * 32 + 4 * lh + (j & 3) + 8 * (j >> 2);
        int col = n0 + nb * 32 + lr;
        out[(size_t)row * 1024 + col] = acc[mb][nb][j] * INV_WSCALE;
      }
}

// ---- fallback (ws too small for t2): R12-style in-GEMM tanh, chunk-level sync
__global__ __launch_bounds__(512, 2) void cheby_gemm_fb(const float* __restrict__ x,
                                                        const f16* __restrict__ wt,
                                                        float* __restrict__ out) {
  __shared__ f16 bbuf[18][4096];
  const int tid  = threadIdx.x;
  const int wid  = tid >> 6;
  const int lane = tid & 63;
  const int lr   = lane & 31;
  const int lh   = lane >> 5;
  const int wm   = wid >> 1;
  const int wn   = wid & 1;
  const int mrow = blockIdx.x >> 3;
  const int ncol = blockIdx.x & 7;
  const int m0   = mrow * 256 + wm * 64;
  const int n0   = ncol * 128 + wn * 64;
  const int rbase = wn * 2048 + ((lane & 15) * 4 + ((lane >> 4) ^ ((lane >> 1) & 3))) * 8;

  auto stage = [&](int cn, int dn, int buf) {
    const f16* src = wt + (size_t)(dn * 32 + cn) * 32768 + (size_t)ncol * 4096;
    __builtin_amdgcn_global_load_lds(
        (const __attribute__((address_space(1))) unsigned*)(src + tid * 8),
        (__attribute__((address_space(3))) unsigned*)(&bbuf[buf][wid * 512]),
        16, 0, 0);
  };
  auto stage9 = [&](int cn, int b0) {
#pragma unroll
    for (int d = 0; d < 9; ++d) stage(cn, d, b0 + d);
  };

  f32x16 acc[2][2];
#pragma unroll
  for (int a = 0; a < 2; ++a)
#pragma unroll
    for (int b = 0; b < 2; ++b)
#pragma unroll
      for (int j = 0; j < 16; ++j) acc[a][b][j] = 0.f;

  const f16x8 ones  = {(f16)1,(f16)1,(f16)1,(f16)1,(f16)1,(f16)1,(f16)1,(f16)1};
  const f16x8 half8 = {(f16)0.5f,(f16)0.5f,(f16)0.5f,(f16)0.5f,
                       (f16)0.5f,(f16)0.5f,(f16)0.5f,(f16)0.5f};
  f16x8 t2v[2][2], t2n[2][2];
  f32x4 xf[2][2][2];

  auto loadx = [&](int cn) {
#pragma unroll
    for (int mb = 0; mb < 2; ++mb)
#pragma unroll
      for (int h = 0; h < 2; ++h) {
        const float* p = x + (size_t)(m0 + mb * 32 + lr) * 1024 + cn * 32 + h * 16 + lh * 8;
        xf[mb][h][0] = *(const f32x4*)p;
        xf[mb][h][1] = *(const f32x4*)(p + 4);
      }
  };
  auto dotanh = [&]() {
#pragma unroll
    for (int mb = 0; mb < 2; ++mb)
#pragma unroll
      for (int h = 0; h < 2; ++h) {
        float tf[8];
#pragma unroll
        for (int e = 0; e < 8; ++e) {
          float xx = (e < 4) ? xf[mb][h][0][e] : xf[mb][h][1][e - 4];
          tf[e] = 1.f - 2.f * __builtin_amdgcn_rcpf(__expf(2.f * xx) + 1.f);
        }
        F16x8u u;
#pragma unroll
        for (int q = 0; q < 4; ++q)
          u.h2[q] = __builtin_amdgcn_cvt_pkrtz(tf[2 * q], tf[2 * q + 1]);
        t2n[mb][h] = u.v8 + u.v8;
      }
  };

#define REC(NEW, S1, S2)                                                       \
  _Pragma("unroll") for (int mb = 0; mb < 2; ++mb)                             \
    _Pragma("unroll") for (int h = 0; h < 2; ++h)                              \
      NEW[mb][h] = __builtin_elementwise_fma(t2v[mb][h], S1[mb][h], -S2[mb][h]);
#define CLUSTER(AF, DIDX)                                                      \
  {                                                                            \
    const f16* bb = &bbuf[0][0] + sbase + (DIDX) * 4096 + rbase;               \
    f16x8 bf[2][2];                                                            \
    _Pragma("unroll") for (int nb = 0; nb < 2; ++nb)                           \
      _Pragma("unroll") for (int h = 0; h < 2; ++h)                            \
        bf[nb][h] = *(const f16x8*)&bb[nb * 1024 + h * 512];                   \
    _Pragma("unroll") for (int nb = 0; nb < 2; ++nb)                           \
      _Pragma("unroll") for (int mb = 0; mb < 2; ++mb) {                       \
        acc[mb][nb] = __builtin_amdgcn_mfma_f32_32x32x16_f16(AF[mb][0], bf[nb][0], \
                                                             acc[mb][nb], 0, 0, 0); \
        acc[mb][nb] = __builtin_amdgcn_mfma_f32_32x32x16_f16(AF[mb][1], bf[nb][1], \
                                                             acc[mb][nb], 0, 0, 0); \
      }                                                                        \
  }

  stage9(0, 0);
  loadx(0);
  dotanh();

  f16x8 onesA[2][2];
#pragma unroll
  for (int mb = 0; mb < 2; ++mb)
#pragma unroll
    for (int h = 0; h < 2; ++h) onesA[mb][h] = ones;

  for (int c = 0; c < 32; ++c) {
    const bool lastc = (c == 31);
    const int  sbase = (c & 1) * 36864;
    const int  nbase = (1 - (c & 1)) * 9;

    asm volatile("s_waitcnt vmcnt(8)" ::: "memory");
    __builtin_amdgcn_s_barrier();

    f16x8 A1[2][2], A2[2][2], A3[2][2], A4[2][2], A5[2][2], A6[2][2], A7[2][2], A8[2][2];
#pragma unroll
    for (int mb = 0; mb < 2; ++mb)
#pragma unroll
      for (int h = 0; h < 2; ++h) {
        t2v[mb][h] = t2n[mb][h];
        A1[mb][h]  = t2v[mb][h] * half8;
      }
    if (!lastc) { stage9(c + 1, nbase); loadx(c + 1); }

    CLUSTER(onesA, 0)
    CLUSTER(A1, 1)
    REC(A2, A1, onesA)  CLUSTER(A2, 2)
    REC(A3, A2, A1)     CLUSTER(A3, 3)
    REC(A4, A3, A2)     CLUSTER(A4, 4)
    REC(A5, A4, A3)     CLUSTER(A5, 5)
    REC(A6, A5, A4)     CLUSTER(A6, 6)
    REC(A7, A6, A5)     CLUSTER(A7, 7)
    REC(A8, A7, A6)     CLUSTER(A8, 8)
    if (!lastc) dotanh();
  }
#undef REC
#undef CLUSTER

#pragma unroll
  for (int mb = 0; mb < 2; ++mb)
#pragma unroll
    for (int nb = 0; nb < 2; ++nb)
#pragma unroll
      for (int j = 0; j < 16; ++j) {
        int row = m0 + mb * 32 + 4 * lh + (j & 3) + 8 * (j >> 2);
        int col = n0 + nb * 32 + lr;
        out[(size_t)row * 1024 + col] = acc[mb][nb][j] * INV_WSCALE;
      }
}

extern "C" void kernel_launch(void* const* d_in, const int* in_sizes, int n_in,
                              void* d_out, int out_size, void* d_ws, size_t ws_size,
                              hipStream_t stream) {
  const float* x  = (const float*)d_in[0];
  const float* cc = (const float*)d_in[1];
  f16*   wt  = (f16*)d_ws;                        // 18,874,368 B
  f16*   t2  = (f16*)((char*)d_ws + 18874368);    // 33,554,432 B
  float* out = (float*)d_out;

  hipLaunchKernelGGL(wt_transform, dim3(1152), dim3(256), 0, stream, cc, wt);
  if (ws_size >= 52428800) {
    hipLaunchKernelGGL(t2_transform, dim3(8192), dim3(256), 0, stream, x, t2);
    hipLaunchKernelGGL(cheby_gemm, dim3(512), dim3(512), 0, stream, t2, wt, out);
  } else {
    hipLaunchKernelGGL(cheby_gemm_fb, dim3(512), dim3(512), 0, stream, x, wt, out);
  }
}

// Round 19
// 331.663 us; speedup vs baseline: 1.0078x; 1.0078x over previous
//
#include <hip/hip_runtime.h>
#include <hip/hip_bf16.h>

// ChebyKAN: y[b,o] = sum_{i,d} T_d(tanh(x[b,i])) * W[i,o,d]
// GEMM M=16384, N=1024, K=9216 with generated A (packed-fp16 Chebyshev recurrence).
// R15: occupancy fix. R14 showed the blocker is unified VGPR (156/wave -> 3
//      waves/SIMD) + block granularity (512-thr = 2 waves/SIMD -> 1 block/CU).
//      Now: 256-thr blocks (1 wave/SIMD) x 3 blocks/CU, tile 128x128 (wave
//      64x64, per-wave math identical), LDS = 5-slot ring x 8KB = 40KB
//      (stage 1 buf 4 steps ahead, 2 gload_lds/phase). Fine phases with
//      counted vmcnt: d in {1,2,3} -> 8, else 4; peeled tail 4,4,4,4,4,4,2,0.

#define WSCALE 4096.0f
#define INV_WSCALE (1.0f/4096.0f)

typedef _Float16 f16;
typedef __fp16   hf2  __attribute__((ext_vector_type(2)));
typedef _Float16 f16x8 __attribute__((ext_vector_type(8)));
typedef float    f32x4 __attribute__((ext_vector_type(4)));
typedef float    f32x16 __attribute__((ext_vector_type(16)));

union F16x8u { hf2 h2[4]; f16x8 v8; };

// ---- kernel 1: repack cc [I][O][9] f32 -> wt (R5 conflict-free layout)
__global__ __launch_bounds__(256) void wt_transform(const float* __restrict__ cc,
                                                    f16* __restrict__ wt) {
  int t    = blockIdx.x * 256 + threadIdx.x;   // 294912 threads
  int j4   = t & 127;
  int grp  = t >> 7;
  int ncol = grp & 7;
  int rest = grp >> 3;
  int ic   = rest & 31;
  int d    = rest >> 5;                        // 0..8
  int u    = j4 >> 5;
  int h    = (j4 >> 4) & 1;
  int r    = j4 & 15;
  int rk   = (r >> 1) & 3;
  size_t base = (size_t)(d * 32 + ic) * 32768 + (size_t)ncol * 4096 + (size_t)j4 * 32;
#pragma unroll
  for (int v = 0; v < 4; ++v) {
    int tt = v ^ rk;
    int q  = tt & 1, kl = tt >> 1;
    int o  = ncol * 128 + u * 32 + q * 16 + r;
    int ib = ic * 32 + h * 16 + kl * 8;
    f16x8 val;
#pragma unroll
    for (int e = 0; e < 8; ++e)
      val[e] = (f16)(cc[((size_t)(ib + e) * 1024 + o) * 9 + d] * WSCALE);
    *(f16x8*)(wt + base + v * 8) = val;
  }
}

// ---- kernel 1b: t2 = 2*tanh(x) as f16
__global__ __launch_bounds__(256) void t2_transform(const float* __restrict__ x,
                                                    f16* __restrict__ t2) {
  size_t gid = (size_t)blockIdx.x * 256 + threadIdx.x;   // 2,097,152 threads
  const float* p = x + gid * 8;
  f32x4 a = *(const f32x4*)p;
  f32x4 b = *(const f32x4*)(p + 4);
  float tf[8];
#pragma unroll
  for (int e = 0; e < 8; ++e) {
    float xx = (e < 4) ? a[e] : b[e - 4];
    tf[e] = 1.f - 2.f * __builtin_amdgcn_rcpf(__expf(2.f * xx) + 1.f);
  }
  F16x8u u;
#pragma unroll
  for (int q = 0; q < 4; ++q)
    u.h2[q] = __builtin_amdgcn_cvt_pkrtz(tf[2 * q], tf[2 * q + 1]);
  f16x8 v = u.v8 + u.v8;
  *(f16x8*)(t2 + gid * 8) = v;
}

// ---- kernel 2: fused basis-gen + GEMM, 128x128 tile, 4 waves of 64m x 64n
__global__ __launch_bounds__(256, 3) void cheby_gemm(const f16* __restrict__ t2g,
                                                     const f16* __restrict__ wt,
                                                     float* __restrict__ out) {
  __shared__ f16 bbuf[5][4096];               // 5-slot ring x 8KB = 40KB -> 3 blocks/CU

  const int tid  = threadIdx.x;
  const int wid  = tid >> 6;                  // 0..3
  const int lane = tid & 63;
  const int lr   = lane & 31;
  const int lh   = lane >> 5;
  const int wm   = wid >> 1;
  const int wn   = wid & 1;
  const int mrow = blockIdx.x >> 3;           // 0..127
  const int ncol = blockIdx.x & 7;            // XCD-affine: wt slice L2-resident
  const int m0   = mrow * 128 + wm * 64;
  const int n0   = ncol * 128 + wn * 64;
  const int rbase = wn * 2048 + ((lane & 15) * 4 + ((lane >> 4) ^ ((lane >> 1) & 3))) * 8;

  // stage one 8KB degree-buf: 2 x global_load_lds (256 thr x 16B each)
  auto stage = [&](int cn, int dn, int slot) {
    const f16* src = wt + (size_t)(dn * 32 + cn) * 32768 + (size_t)ncol * 4096;
    __builtin_amdgcn_global_load_lds(
        (const __attribute__((address_space(1))) unsigned*)(src + tid * 8),
        (__attribute__((address_space(3))) unsigned*)(&bbuf[slot][wid * 512]),
        16, 0, 0);
    __builtin_amdgcn_global_load_lds(
        (const __attribute__((address_space(1))) unsigned*)(src + 2048 + tid * 8),
        (__attribute__((address_space(3))) unsigned*)(&bbuf[slot][wid * 512 + 2048]),
        16, 0, 0);
  };

  f32x16 acc[2][2];
#pragma unroll
  for (int a = 0; a < 2; ++a)
#pragma unroll
    for (int b = 0; b < 2; ++b)
#pragma unroll
      for (int j = 0; j < 16; ++j) acc[a][b][j] = 0.f;

  const f16x8 ones  = {(f16)1,(f16)1,(f16)1,(f16)1,(f16)1,(f16)1,(f16)1,(f16)1};
  const f16x8 half8 = {(f16)0.5f,(f16)0.5f,(f16)0.5f,(f16)0.5f,
                       (f16)0.5f,(f16)0.5f,(f16)0.5f,(f16)0.5f};
  f16x8 t2v[2][2], t2n[2][2];

  auto loadx = [&](int cn) {   // 4 VMEM f16x8 -> t2n
#pragma unroll
    for (int mb = 0; mb < 2; ++mb)
#pragma unroll
      for (int h = 0; h < 2; ++h)
        t2n[mb][h] = *(const f16x8*)(t2g + (size_t)(m0 + mb * 32 + lr) * 1024
                                         + cn * 32 + h * 16 + lh * 8);
  };

#define REC(NEW, S1, S2)                                                       \
  _Pragma("unroll") for (int mb = 0; mb < 2; ++mb)                             \
    _Pragma("unroll") for (int h = 0; h < 2; ++h)                              \
      NEW[mb][h] = __builtin_elementwise_fma(t2v[mb][h], S1[mb][h], -S2[mb][h]);

#define LOADB(BD, SLOT)                                                        \
  {                                                                            \
    const f16* bb = &bbuf[0][0] + (SLOT) * 4096 + rbase;                       \
    BD[0][0] = *(const f16x8*)&bb[0];    BD[0][1] = *(const f16x8*)&bb[512];   \
    BD[1][0] = *(const f16x8*)&bb[1024]; BD[1][1] = *(const f16x8*)&bb[1536];  \
  }

#define MFMA8(AF, BD)                                                          \
  {                                                                            \
    _Pragma("unroll") for (int nb = 0; nb < 2; ++nb)                           \
      _Pragma("unroll") for (int mb = 0; mb < 2; ++mb) {                       \
        acc[mb][nb] = __builtin_amdgcn_mfma_f32_32x32x16_f16(AF[mb][0], BD[nb][0], \
                                                             acc[mb][nb], 0, 0, 0); \
        acc[mb][nb] = __builtin_amdgcn_mfma_f32_32x32x16_f16(AF[mb][1], BD[nb][1], \
                                                             acc[mb][nb], 0, 0, 0); \
      }                                                                        \
  }

#define VMB(N)                                                                 \
  asm volatile("s_waitcnt vmcnt(" #N ")" ::: "memory");                        \
  __builtin_amdgcn_s_barrier();

  // prologue: loadx(0) then stage steps 0..3 -> slots 0..3
  loadx(0);
  int p0 = 0, p1 = 1, p2 = 2, p3 = 3, p4 = 4;
  stage(0, 0, p0); stage(0, 1, p1); stage(0, 2, p2); stage(0, 3, p3);

  f16x8 onesA[2][2];
#pragma unroll
  for (int mb = 0; mb < 2; ++mb)
#pragma unroll
    for (int h = 0; h < 2; ++h) onesA[mb][h] = ones;

  f16x8 bfA[2][2], bfB[2][2];
  f16x8 A1[2][2], A2[2][2], A3[2][2], A4[2][2], A5[2][2], A6[2][2], A7[2][2], A8[2][2];

  for (int c = 0; c < 31; ++c) {
    // d=0: prove stage(9c), stage(9c+1), loadx(c)   [queue: 2 stages after = 4]
    VMB(4)
    LOADB(bfA, p0)
#pragma unroll
    for (int mb = 0; mb < 2; ++mb)
#pragma unroll
      for (int h = 0; h < 2; ++h) {
        t2v[mb][h] = t2n[mb][h];            // adopt chunk-c t2 (before loadx!)
        A1[mb][h]  = t2v[mb][h] * half8;
      }
    stage(c, 4, p4);
    loadx(c + 1);
    LOADB(bfB, p1)
    MFMA8(onesA, bfA)

    VMB(8) stage(c, 5, p0); LOADB(bfA, p2) REC(A2, A1, onesA) MFMA8(A1, bfB)   // d=1
    VMB(8) stage(c, 6, p1); LOADB(bfB, p3) REC(A3, A2, A1)    MFMA8(A2, bfA)   // d=2
    VMB(8) stage(c, 7, p2); LOADB(bfA, p4) REC(A4, A3, A2)    MFMA8(A3, bfB)   // d=3
    VMB(4) stage(c, 8, p3); LOADB(bfB, p0) REC(A5, A4, A3)    MFMA8(A4, bfA)   // d=4
    VMB(4) stage(c + 1, 0, p4); LOADB(bfA, p1) REC(A6, A5, A4) MFMA8(A5, bfB)  // d=5
    VMB(4) stage(c + 1, 1, p0); LOADB(bfB, p2) REC(A7, A6, A5) MFMA8(A6, bfA)  // d=6
    VMB(4) stage(c + 1, 2, p1); LOADB(bfA, p3) REC(A8, A7, A6) MFMA8(A7, bfB)  // d=7
    stage(c + 1, 3, p2);                                                       // d=8
    MFMA8(A8, bfA)

    // rotate ring base: slot(9(c+1)+k) = p[(k+4)%5]
    int tmp = p4; p4 = p3; p3 = p2; p2 = p1; p1 = p0; p0 = tmp;
  }

  // ---- tail chunk c=31: stages only for steps <= 287 (d<=4), no loadx
  {
    VMB(4)
    LOADB(bfA, p0)
#pragma unroll
    for (int mb = 0; mb < 2; ++mb)
#pragma unroll
      for (int h = 0; h < 2; ++h) {
        t2v[mb][h] = t2n[mb][h];
        A1[mb][h]  = t2v[mb][h] * half8;
      }
    stage(31, 4, p4);
    LOADB(bfB, p1)
    MFMA8(onesA, bfA)

    VMB(4) stage(31, 5, p0); LOADB(bfA, p2) REC(A2, A1, onesA) MFMA8(A1, bfB)  // d=1
    VMB(4) stage(31, 6, p1); LOADB(bfB, p3) REC(A3, A2, A1)    MFMA8(A2, bfA)  // d=2
    VMB(4) stage(31, 7, p2); LOADB(bfA, p4) REC(A4, A3, A2)    MFMA8(A3, bfB)  // d=3
    VMB(4) stage(31, 8, p3); LOADB(bfB, p0) REC(A5, A4, A3)    MFMA8(A4, bfA)  // d=4
    VMB(4) LOADB(bfA, p1) REC(A6, A5, A4) MFMA8(A5, bfB)                       // d=5
    VMB(2) LOADB(bfB, p2) REC(A7, A6, A5) MFMA8(A6, bfA)                       // d=6
    VMB(0) LOADB(bfA, p3) REC(A8, A7, A6) MFMA8(A7, bfB)                       // d=7
    MFMA8(A8, bfA)                                                             // d=8
  }
#undef REC
#undef LOADB
#undef MFMA8
#undef VMB

  // epilogue: 32x32 C/D map: col = lane&31, row = (j&3) + 8*(j>>2) + 4*(lane>>5)
#pragma unroll
  for (int mb = 0; mb < 2; ++mb)
#pragma unroll
    for (int nb = 0; nb < 2; ++nb)
#pragma unroll
      for (int j = 0; j < 16; ++j) {
        int row = m0 + mb * 32 + 4 * lh + (j & 3) + 8 * (j >> 2);
        int col = n0 + nb * 32 + lr;
        out[(size_t)row * 1024 + col] = acc[mb][nb][j] * INV_WSCALE;
      }
}

// ---- fallback (ws too small for t2): R12-style in-GEMM tanh, chunk-level sync
__global__ __launch_bounds__(512, 2) void cheby_gemm_fb(const float* __restrict__ x,
                                                        const f16* __restrict__ wt,
                                                        float* __restrict__ out) {
  __shared__ f16 bbuf[18][4096];
  const int tid  = threadIdx.x;
  const int wid  = tid >> 6;
  const int lane = tid & 63;
  const int lr   = lane & 31;
  const int lh   = lane >> 5;
  const int wm   = wid >> 1;
  const int wn   = wid & 1;
  const int mrow = blockIdx.x >> 3;
  const int ncol = blockIdx.x & 7;
  const int m0   = mrow * 256 + wm * 64;
  const int n0   = ncol * 128 + wn * 64;
  const int rbase = wn * 2048 + ((lane & 15) * 4 + ((lane >> 4) ^ ((lane >> 1) & 3))) * 8;

  auto stage = [&](int cn, int dn, int buf) {
    const f16* src = wt + (size_t)(dn * 32 + cn) * 32768 + (size_t)ncol * 4096;
    __builtin_amdgcn_global_load_lds(
        (const __attribute__((address_space(1))) unsigned*)(src + tid * 8),
        (__attribute__((address_space(3))) unsigned*)(&bbuf[buf][wid * 512]),
        16, 0, 0);
  };
  auto stage9 = [&](int cn, int b0) {
#pragma unroll
    for (int d = 0; d < 9; ++d) stage(cn, d, b0 + d);
  };

  f32x16 acc[2][2];
#pragma unroll
  for (int a = 0; a < 2; ++a)
#pragma unroll
    for (int b = 0; b < 2; ++b)
#pragma unroll
      for (int j = 0; j < 16; ++j) acc[a][b][j] = 0.f;

  const f16x8 ones  = {(f16)1,(f16)1,(f16)1,(f16)1,(f16)1,(f16)1,(f16)1,(f16)1};
  const f16x8 half8 = {(f16)0.5f,(f16)0.5f,(f16)0.5f,(f16)0.5f,
                       (f16)0.5f,(f16)0.5f,(f16)0.5f,(f16)0.5f};
  f16x8 t2v[2][2], t2n[2][2];
  f32x4 xf[2][2][2];

  auto loadx = [&](int cn) {
#pragma unroll
    for (int mb = 0; mb < 2; ++mb)
#pragma unroll
      for (int h = 0; h < 2; ++h) {
        const float* p = x + (size_t)(m0 + mb * 32 + lr) * 1024 + cn * 32 + h * 16 + lh * 8;
        xf[mb][h][0] = *(const f32x4*)p;
        xf[mb][h][1] = *(const f32x4*)(p + 4);
      }
  };
  auto dotanh = [&]() {
#pragma unroll
    for (int mb = 0; mb < 2; ++mb)
#pragma unroll
      for (int h = 0; h < 2; ++h) {
        float tf[8];
#pragma unroll
        for (int e = 0; e < 8; ++e) {
          float xx = (e < 4) ? xf[mb][h][0][e] : xf[mb][h][1][e - 4];
          tf[e] = 1.f - 2.f * __builtin_amdgcn_rcpf(__expf(2.f * xx) + 1.f);
        }
        F16x8u u;
#pragma unroll
        for (int q = 0; q < 4; ++q)
          u.h2[q] = __builtin_amdgcn_cvt_pkrtz(tf[2 * q], tf[2 * q + 1]);
        t2n[mb][h] = u.v8 + u.v8;
      }
  };

#define REC(NEW, S1, S2)                                                       \
  _Pragma("unroll") for (int mb = 0; mb < 2; ++mb)                             \
    _Pragma("unroll") for (int h = 0; h < 2; ++h)                              \
      NEW[mb][h] = __builtin_elementwise_fma(t2v[mb][h], S1[mb][h], -S2[mb][h]);
#define CLUSTER(AF, DIDX)                                                      \
  {                                                                            \
    const f16* bb = &bbuf[0][0] + sbase + (DIDX) * 4096 + rbase;               \
    f16x8 bf[2][2];                                                            \
    _Pragma("unroll") for (int nb = 0; nb < 2; ++nb)                           \
      _Pragma("unroll") for (int h = 0; h < 2; ++h)                            \
        bf[nb][h] = *(const f16x8*)&bb[nb * 1024 + h * 512];                   \
    _Pragma("unroll") for (int nb = 0; nb < 2; ++nb)                           \
      _Pragma("unroll") for (int mb = 0; mb < 2; ++mb) {                       \
        acc[mb][nb] = __builtin_amdgcn_mfma_f32_32x32x16_f16(AF[mb][0], bf[nb][0], \
                                                             acc[mb][nb], 0, 0, 0); \
        acc[mb][nb] = __builtin_amdgcn_mfma_f32_32x32x16_f16(AF[mb][1], bf[nb][1], \
                                                             acc[mb][nb], 0, 0, 0); \
      }                                                                        \
  }

  stage9(0, 0);
  loadx(0);
  dotanh();

  f16x8 onesA[2][2];
#pragma unroll
  for (int mb = 0; mb < 2; ++mb)
#pragma unroll
    for (int h = 0; h < 2; ++h) onesA[mb][h] = ones;

  for (int c = 0; c < 32; ++c) {
    const bool lastc = (c == 31);
    const int  sbase = (c & 1) * 36864;
    const int  nbase = (1 - (c & 1)) * 9;

    asm volatile("s_waitcnt vmcnt(8)" ::: "memory");
    __builtin_amdgcn_s_barrier();

    f16x8 A1[2][2], A2[2][2], A3[2][2], A4[2][2], A5[2][2], A6[2][2], A7[2][2], A8[2][2];
#pragma unroll
    for (int mb = 0; mb < 2; ++mb)
#pragma unroll
      for (int h = 0; h < 2; ++h) {
        t2v[mb][h] = t2n[mb][h];
        A1[mb][h]  = t2v[mb][h] * half8;
      }
    if (!lastc) { stage9(c + 1, nbase); loadx(c + 1); }

    CLUSTER(onesA, 0)
    CLUSTER(A1, 1)
    REC(A2, A1, onesA)  CLUSTER(A2, 2)
    REC(A3, A2, A1)     CLUSTER(A3, 3)
    REC(A4, A3, A2)     CLUSTER(A4, 4)
    REC(A5, A4, A3)     CLUSTER(A5, 5)
    REC(A6, A5, A4)     CLUSTER(A6, 6)
    REC(A7, A6, A5)     CLUSTER(A7, 7)
    REC(A8, A7, A6)     CLUSTER(A8, 8)
    if (!lastc) dotanh();
  }
#undef REC
#undef CLUSTER

#pragma unroll
  for (int mb = 0; mb < 2; ++mb)
#pragma unroll
    for (int nb = 0; nb < 2; ++nb)
#pragma unroll
      for (int j = 0; j < 16; ++j) {
        int row = m0 + mb * 32 + 4 * lh + (j & 3) + 8 * (j >> 2);
        int col = n0 + nb * 32 + lr;
        out[(size_t)row * 1024 + col] = acc[mb][nb][j] * INV_WSCALE;
      }
}

extern "C" void kernel_launch(void* const* d_in, const int* in_sizes, int n_in,
                              void* d_out, int out_size, void* d_ws, size_t ws_size,
                              hipStream_t stream) {
  const float* x  = (const float*)d_in[0];
  const float* cc = (const float*)d_in[1];
  f16*   wt  = (f16*)d_ws;                        // 18,874,368 B
  f16*   t2  = (f16*)((char*)d_ws + 18874368);    // 33,554,432 B
  float* out = (float*)d_out;

  hipLaunchKernelGGL(wt_transform, dim3(1152), dim3(256), 0, stream, cc, wt);
  if (ws_size >= 52428800) {
    hipLaunchKernelGGL(t2_transform, dim3(8192), dim3(256), 0, stream, x, t2);
    hipLaunchKernelGGL(cheby_gemm, dim3(1024), dim3(256), 0, stream, t2, wt, out);
  } else {
    hipLaunchKernelGGL(cheby_gemm_fb, dim3(512), dim3(512), 0, stream, x, wt, out);
  }
}

// Round 20
// 300.965 us; speedup vs baseline: 1.1106x; 1.1020x over previous
//
#include <hip/hip_runtime.h>
#include <hip/hip_bf16.h>

// ChebyKAN: y[b,o] = sum_{i,d} T_d(tanh(x[b,i])) * W[i,o,d]
// GEMM M=16384, N=1024, K=9216 with generated A (packed-fp16 Chebyshev recurrence).
// R16: (a) GEMM depth-2 B prefetch: ring-6 (48KB, 3 blocks/CU), 3 rotating bf
//      sets, stage depth 5; waits re-derived (PH0..8 = 4,4,8,8,8,4,4,4,4).
//      (b) wt_transform rewritten as LDS transpose: coalesced reads (72B runs)
//      + f16x2 LDS scatter + coalesced 16B stores (was 9.4M scattered gathers).

#define WSCALE 4096.0f
#define INV_WSCALE (1.0f/4096.0f)

typedef _Float16 f16;
typedef __fp16   hf2  __attribute__((ext_vector_type(2)));
typedef _Float16 f16x2v __attribute__((ext_vector_type(2)));
typedef _Float16 f16x8 __attribute__((ext_vector_type(8)));
typedef float    f32x4 __attribute__((ext_vector_type(4)));
typedef float    f32x4u __attribute__((ext_vector_type(4), aligned(4)));
typedef float    f32x2u __attribute__((ext_vector_type(2), aligned(4)));
typedef float    f32x16 __attribute__((ext_vector_type(16)));

union F16x8u { hf2 h2[4]; f16x8 v8; };

// ---- kernel 1 (v2): repack cc [I][O][9] f32 -> wt (R5 layout) via LDS transpose.
// block = (ic, ncol, u): reads 32i x 32o x 9d slab with contiguous 72B runs,
// writes 1152 x 16B chunks coalesced.
__global__ __launch_bounds__(256) void wt_transform(const float* __restrict__ cc,
                                                    f16* __restrict__ wt) {
  __shared__ f16 s16[9216];                    // 18,432 B
  const int bid  = blockIdx.x;                 // 1024 blocks
  const int u    = bid & 3;
  const int ncol = (bid >> 2) & 7;
  const int ic   = bid >> 5;
  const int t    = threadIdx.x;
  const int i2   = t >> 4;                     // i-pair 0..15
  const int o2   = t & 15;                     // o-pair 0..15
  const int i0   = i2 * 2, o0 = o2 * 2;
  const int h    = i0 >> 4;
  const int kl   = (i0 >> 3) & 1;
  const int e    = i0 & 7;                     // even

  float va[2][18];
#pragma unroll
  for (int ii = 0; ii < 2; ++ii) {
    const float* g = cc + ((size_t)(ic * 32 + i0 + ii) * 1024
                           + (ncol * 128 + u * 32 + o0)) * 9;
    f32x4u a = *(const f32x4u*)(g);
    f32x4u b = *(const f32x4u*)(g + 4);
    f32x4u c4 = *(const f32x4u*)(g + 8);
    f32x4u d4 = *(const f32x4u*)(g + 12);
    f32x2u e2 = *(const f32x2u*)(g + 16);
#pragma unroll
    for (int j = 0; j < 4; ++j) { va[ii][j] = a[j]; va[ii][4 + j] = b[j];
                                  va[ii][8 + j] = c4[j]; va[ii][12 + j] = d4[j]; }
    va[ii][16] = e2[0]; va[ii][17] = e2[1];
  }

#pragma unroll
  for (int oo = 0; oo < 2; ++oo) {
    const int ol = o0 + oo;
    const int r  = ol & 15, q = ol >> 4;
    const int rk = (r >> 1) & 3;
    const int vsl = (kl * 2 + q) ^ rk;
    const int jj = h * 16 + r;
#pragma unroll
    for (int d = 0; d < 9; ++d) {
      f16x2v pv = { (f16)(va[0][oo * 9 + d] * WSCALE),
                    (f16)(va[1][oo * 9 + d] * WSCALE) };
      *(f16x2v*)(&s16[(d * 128 + jj * 4 + vsl) * 8 + e]) = pv;
    }
  }
  __syncthreads();

#pragma unroll
  for (int w = 0; w < 5; ++w) {
    int cidx = t + 256 * w;
    if (cidx < 1152) {
      f16x8 val = *(const f16x8*)(&s16[cidx * 8]);
      int d = cidx >> 7, rem = cidx & 127;
      *(f16x8*)(wt + (size_t)((d * 32 + ic) * 8 + ncol) * 4096 + u * 1024 + rem * 8) = val;
    }
  }
}

// ---- kernel 1b: t2 = 2*tanh(x) as f16
__global__ __launch_bounds__(256) void t2_transform(const float* __restrict__ x,
                                                    f16* __restrict__ t2) {
  size_t gid = (size_t)blockIdx.x * 256 + threadIdx.x;   // 2,097,152 threads
  const float* p = x + gid * 8;
  f32x4 a = *(const f32x4*)p;
  f32x4 b = *(const f32x4*)(p + 4);
  float tf[8];
#pragma unroll
  for (int e = 0; e < 8; ++e) {
    float xx = (e < 4) ? a[e] : b[e - 4];
    tf[e] = 1.f - 2.f * __builtin_amdgcn_rcpf(__expf(2.f * xx) + 1.f);
  }
  F16x8u u;
#pragma unroll
  for (int q = 0; q < 4; ++q)
    u.h2[q] = __builtin_amdgcn_cvt_pkrtz(tf[2 * q], tf[2 * q + 1]);
  f16x8 v = u.v8 + u.v8;
  *(f16x8*)(t2 + gid * 8) = v;
}

// ---- kernel 2: fused basis-gen + GEMM, 128x128 tile, 4 waves of 64m x 64n
__global__ __launch_bounds__(256, 3) void cheby_gemm(const f16* __restrict__ t2g,
                                                     const f16* __restrict__ wt,
                                                     float* __restrict__ out) {
  __shared__ f16 bbuf[6][4096];               // ring of 6 x 8KB = 48KB -> 3 blocks/CU

  const int tid  = threadIdx.x;
  const int wid  = tid >> 6;
  const int lane = tid & 63;
  const int lr   = lane & 31;
  const int lh   = lane >> 5;
  const int wm   = wid >> 1;
  const int wn   = wid & 1;
  const int mrow = blockIdx.x >> 3;
  const int ncol = blockIdx.x & 7;
  const int m0   = mrow * 128 + wm * 64;
  const int n0   = ncol * 128 + wn * 64;
  const int rbase = wn * 2048 + ((lane & 15) * 4 + ((lane >> 4) ^ ((lane >> 1) & 3))) * 8;

  auto stage = [&](int cn, int dn, int slot) {
    const f16* src = wt + (size_t)(dn * 32 + cn) * 32768 + (size_t)ncol * 4096;
    __builtin_amdgcn_global_load_lds(
        (const __attribute__((address_space(1))) unsigned*)(src + tid * 8),
        (__attribute__((address_space(3))) unsigned*)(&bbuf[slot][wid * 512]),
        16, 0, 0);
    __builtin_amdgcn_global_load_lds(
        (const __attribute__((address_space(1))) unsigned*)(src + 2048 + tid * 8),
        (__attribute__((address_space(3))) unsigned*)(&bbuf[slot][wid * 512 + 2048]),
        16, 0, 0);
  };

  f32x16 acc[2][2];
#pragma unroll
  for (int a = 0; a < 2; ++a)
#pragma unroll
    for (int b = 0; b < 2; ++b)
#pragma unroll
      for (int j = 0; j < 16; ++j) acc[a][b][j] = 0.f;

  const f16x8 ones  = {(f16)1,(f16)1,(f16)1,(f16)1,(f16)1,(f16)1,(f16)1,(f16)1};
  const f16x8 half8 = {(f16)0.5f,(f16)0.5f,(f16)0.5f,(f16)0.5f,
                       (f16)0.5f,(f16)0.5f,(f16)0.5f,(f16)0.5f};
  f16x8 t2v[2][2], t2n[2][2];

  auto loadx = [&](int cn) {   // 4 VMEM f16x8 -> t2n
#pragma unroll
    for (int mb = 0; mb < 2; ++mb)
#pragma unroll
      for (int h = 0; h < 2; ++h)
        t2n[mb][h] = *(const f16x8*)(t2g + (size_t)(m0 + mb * 32 + lr) * 1024
                                         + cn * 32 + h * 16 + lh * 8);
  };

#define REC(NEW, S1, S2)                                                       \
  _Pragma("unroll") for (int mb = 0; mb < 2; ++mb)                             \
    _Pragma("unroll") for (int h = 0; h < 2; ++h)                              \
      NEW[mb][h] = __builtin_elementwise_fma(t2v[mb][h], S1[mb][h], -S2[mb][h]);

#define LB(BD, SLOT)                                                           \
  {                                                                            \
    const f16* bb = &bbuf[0][0] + (SLOT) * 4096 + rbase;                       \
    BD[0][0] = *(const f16x8*)&bb[0];    BD[0][1] = *(const f16x8*)&bb[512];   \
    BD[1][0] = *(const f16x8*)&bb[1024]; BD[1][1] = *(const f16x8*)&bb[1536];  \
  }

#define M8(AF, BD)                                                             \
  {                                                                            \
    _Pragma("unroll") for (int nb = 0; nb < 2; ++nb)                           \
      _Pragma("unroll") for (int mb = 0; mb < 2; ++mb) {                       \
        acc[mb][nb] = __builtin_amdgcn_mfma_f32_32x32x16_f16(AF[mb][0], BD[nb][0], \
                                                             acc[mb][nb], 0, 0, 0); \
        acc[mb][nb] = __builtin_amdgcn_mfma_f32_32x32x16_f16(AF[mb][1], BD[nb][1], \
                                                             acc[mb][nb], 0, 0, 0); \
      }                                                                        \
  }

#define ADOPT                                                                  \
  _Pragma("unroll") for (int mb = 0; mb < 2; ++mb)                             \
    _Pragma("unroll") for (int h = 0; h < 2; ++h) {                            \
      t2v[mb][h] = t2n[mb][h];                                                 \
      A1[mb][h]  = t2v[mb][h] * half8;                                         \
    }

#define VMB(N)                                                                 \
  asm volatile("s_waitcnt vmcnt(" #N ")" ::: "memory");                        \
  __builtin_amdgcn_s_barrier();

  f16x8 onesA[2][2];
#pragma unroll
  for (int mb = 0; mb < 2; ++mb)
#pragma unroll
    for (int h = 0; h < 2; ++h) onesA[mb][h] = ones;

  f16x8 bf0[2][2], bf1[2][2], bf2[2][2];
  f16x8 A1[2][2], A2[2][2], A3[2][2], A4[2][2], A5[2][2], A6[2][2], A7[2][2], A8[2][2];
  int q0 = 0, q1 = 1, q2 = 2, q3 = 3, q4 = 4, q5 = 5;   // slots of steps 9c+0..9c+5

  // prologue: loadx(0); stage steps 0..4; prove steps 0,1; preload B(0),B(1)
  loadx(0);
  stage(0, 0, 0); stage(0, 1, 1); stage(0, 2, 2); stage(0, 3, 3); stage(0, 4, 4);
  VMB(6)
  LB(bf0, 0) LB(bf1, 1)

  // peeled PH0(c=0): prove step 2; LB step2; adopt; stage step 5; MFMA deg 0
  VMB(4)
  LB(bf2, q2)
  ADOPT
  stage(0, 5, q5);
  M8(onesA, bf0)

  for (int c = 0; c < 31; ++c) {
    // PH1: MFMA deg1; stage step 9c+6; loadx(c+1); LB step 9c+3
    VMB(4) stage(c, 6, q0); loadx(c + 1); LB(bf0, q3) REC(A2, A1, onesA) M8(A1, bf1)
    // PH2..PH8
    VMB(8) stage(c, 7, q1);     LB(bf1, q4) REC(A3, A2, A1) M8(A2, bf2)
    VMB(8) stage(c, 8, q2);     LB(bf2, q5) REC(A4, A3, A2) M8(A3, bf0)
    VMB(8) stage(c + 1, 0, q3); LB(bf0, q0) REC(A5, A4, A3) M8(A4, bf1)
    VMB(4) stage(c + 1, 1, q4); LB(bf1, q1) REC(A6, A5, A4) M8(A5, bf2)
    VMB(4) stage(c + 1, 2, q5); LB(bf2, q2) REC(A7, A6, A5) M8(A6, bf0)
    VMB(4) stage(c + 1, 3, q0); LB(bf0, q3) REC(A8, A7, A6) M8(A7, bf1)
    VMB(4) stage(c + 1, 4, q1); LB(bf1, q4)                 M8(A8, bf2)
    // rotate ring: slots of steps 9(c+1)+k
    { int r0 = q0, r1 = q1, r2 = q2;
      q0 = q3; q1 = q4; q2 = q5; q3 = r0; q4 = r1; q5 = r2; }
    // PH0(c+1): prove step 9(c+1)+2; LB it; adopt; stage step 9(c+1)+5; MFMA deg0
    VMB(4)
    LB(bf2, q2)
    ADOPT
    stage(c + 1, 5, q5);
    M8(onesA, bf0)
  }

  // ---- tail chunk c=31 phases 1..8 (no loadx; stages end at step 287)
  VMB(4) stage(31, 6, q0); LB(bf0, q3) REC(A2, A1, onesA) M8(A1, bf1)
  VMB(4) stage(31, 7, q1); LB(bf1, q4) REC(A3, A2, A1)    M8(A2, bf2)
  VMB(4) stage(31, 8, q2); LB(bf2, q5) REC(A4, A3, A2)    M8(A3, bf0)
  VMB(4) LB(bf0, q0) REC(A5, A4, A3) M8(A4, bf1)
  VMB(2) LB(bf1, q1) REC(A6, A5, A4) M8(A5, bf2)
  VMB(0) LB(bf2, q2) REC(A7, A6, A5) M8(A6, bf0)
  REC(A8, A7, A6) M8(A7, bf1)
  M8(A8, bf2)

#undef REC
#undef LB
#undef M8
#undef ADOPT
#undef VMB

  // epilogue: 32x32 C/D map: col = lane&31, row = (j&3) + 8*(j>>2) + 4*(lane>>5)
#pragma unroll
  for (int mb = 0; mb < 2; ++mb)
#pragma unroll
    for (int nb = 0; nb < 2; ++nb)
#pragma unroll
      for (int j = 0; j < 16; ++j) {
        int row = m0 + mb * 32 + 4 * lh + (j & 3) + 8 * (j >> 2);
        int col = n0 + nb * 32 + lr;
        out[(size_t)row * 1024 + col] = acc[mb][nb][j] * INV_WSCALE;
      }
}

// ---- fallback (ws too small for t2): in-GEMM tanh, chunk-level sync (R12 path)
__global__ __launch_bounds__(512, 2) void cheby_gemm_fb(const float* __restrict__ x,
                                                        const f16* __restrict__ wt,
                                                        float* __restrict__ out) {
  __shared__ f16 bbuf[18][4096];
  const int tid  = threadIdx.x;
  const int wid  = tid >> 6;
  const int lane = tid & 63;
  const int lr   = lane & 31;
  const int lh   = lane >> 5;
  const int wm   = wid >> 1;
  const int wn   = wid & 1;
  const int mrow = blockIdx.x >> 3;
  const int ncol = blockIdx.x & 7;
  const int m0   = mrow * 256 + wm * 64;
  const int n0   = ncol * 128 + wn * 64;
  const int rbase = wn * 2048 + ((lane & 15) * 4 + ((lane >> 4) ^ ((lane >> 1) & 3))) * 8;

  auto stage = [&](int cn, int dn, int buf) {
    const f16* src = wt + (size_t)(dn * 32 + cn) * 32768 + (size_t)ncol * 4096;
    __builtin_amdgcn_global_load_lds(
        (const __attribute__((address_space(1))) unsigned*)(src + tid * 8),
        (__attribute__((address_space(3))) unsigned*)(&bbuf[buf][wid * 512]),
        16, 0, 0);
  };
  auto stage9 = [&](int cn, int b0) {
#pragma unroll
    for (int d = 0; d < 9; ++d) stage(cn, d, b0 + d);
  };

  f32x16 acc[2][2];
#pragma unroll
  for (int a = 0; a < 2; ++a)
#pragma unroll
    for (int b = 0; b < 2; ++b)
#pragma unroll
      for (int j = 0; j < 16; ++j) acc[a][b][j] = 0.f;

  const f16x8 ones  = {(f16)1,(f16)1,(f16)1,(f16)1,(f16)1,(f16)1,(f16)1,(f16)1};
  const f16x8 half8 = {(f16)0.5f,(f16)0.5f,(f16)0.5f,(f16)0.5f,
                       (f16)0.5f,(f16)0.5f,(f16)0.5f,(f16)0.5f};
  f16x8 t2v[2][2], t2n[2][2];
  f32x4 xf[2][2][2];

  auto loadx = [&](int cn) {
#pragma unroll
    for (int mb = 0; mb < 2; ++mb)
#pragma unroll
      for (int h = 0; h < 2; ++h) {
        const float* p = x + (size_t)(m0 + mb * 32 + lr) * 1024 + cn * 32 + h * 16 + lh * 8;
        xf[mb][h][0] = *(const f32x4*)p;
        xf[mb][h][1] = *(const f32x4*)(p + 4);
      }
  };
  auto dotanh = [&]() {
#pragma unroll
    for (int mb = 0; mb < 2; ++mb)
#pragma unroll
      for (int h = 0; h < 2; ++h) {
        float tf[8];
#pragma unroll
        for (int e = 0; e < 8; ++e) {
          float xx = (e < 4) ? xf[mb][h][0][e] : xf[mb][h][1][e - 4];
          tf[e] = 1.f - 2.f * __builtin_amdgcn_rcpf(__expf(2.f * xx) + 1.f);
        }
        F16x8u u;
#pragma unroll
        for (int q = 0; q < 4; ++q)
          u.h2[q] = __builtin_amdgcn_cvt_pkrtz(tf[2 * q], tf[2 * q + 1]);
        t2n[mb][h] = u.v8 + u.v8;
      }
  };

#define REC(NEW, S1, S2)                                                       \
  _Pragma("unroll") for (int mb = 0; mb < 2; ++mb)                             \
    _Pragma("unroll") for (int h = 0; h < 2; ++h)                              \
      NEW[mb][h] = __builtin_elementwise_fma(t2v[mb][h], S1[mb][h], -S2[mb][h]);
#define CLUSTER(AF, DIDX)                                                      \
  {                                                                            \
    const f16* bb = &bbuf[0][0] + sbase + (DIDX) * 4096 + rbase;               \
    f16x8 bf[2][2];                                                            \
    _Pragma("unroll") for (int nb = 0; nb < 2; ++nb)                           \
      _Pragma("unroll") for (int h = 0; h < 2; ++h)                            \
        bf[nb][h] = *(const f16x8*)&bb[nb * 1024 + h * 512];                   \
    _Pragma("unroll") for (int nb = 0; nb < 2; ++nb)                           \
      _Pragma("unroll") for (int mb = 0; mb < 2; ++mb) {                       \
        acc[mb][nb] = __builtin_amdgcn_mfma_f32_32x32x16_f16(AF[mb][0], bf[nb][0], \
                                                             acc[mb][nb], 0, 0, 0); \
        acc[mb][nb] = __builtin_amdgcn_mfma_f32_32x32x16_f16(AF[mb][1], bf[nb][1], \
                                                             acc[mb][nb], 0, 0, 0); \
      }                                                                        \
  }

  stage9(0, 0);
  loadx(0);
  dotanh();

  f16x8 onesA[2][2];
#pragma unroll
  for (int mb = 0; mb < 2; ++mb)
#pragma unroll
    for (int h = 0; h < 2; ++h) onesA[mb][h] = ones;

  for (int c = 0; c < 32; ++c) {
    const bool lastc = (c == 31);
    const int  sbase = (c & 1) * 36864;
    const int  nbase = (1 - (c & 1)) * 9;

    asm volatile("s_waitcnt vmcnt(8)" ::: "memory");
    __builtin_amdgcn_s_barrier();

    f16x8 A1[2][2], A2[2][2], A3[2][2], A4[2][2], A5[2][2], A6[2][2], A7[2][2], A8[2][2];
#pragma unroll
    for (int mb = 0; mb < 2; ++mb)
#pragma unroll
      for (int h = 0; h < 2; ++h) {
        t2v[mb][h] = t2n[mb][h];
        A1[mb][h]  = t2v[mb][h] * half8;
      }
    if (!lastc) { stage9(c + 1, nbase); loadx(c + 1); }

    CLUSTER(onesA, 0)
    CLUSTER(A1, 1)
    REC(A2, A1, onesA)  CLUSTER(A2, 2)
    REC(A3, A2, A1)     CLUSTER(A3, 3)
    REC(A4, A3, A2)     CLUSTER(A4, 4)
    REC(A5, A4, A3)     CLUSTER(A5, 5)
    REC(A6, A5, A4)     CLUSTER(A6, 6)
    REC(A7, A6, A5)     CLUSTER(A7, 7)
    REC(A8, A7, A6)     CLUSTER(A8, 8)
    if (!lastc) dotanh();
  }
#undef REC
#undef CLUSTER

#pragma unroll
  for (int mb = 0; mb < 2; ++mb)
#pragma unroll
    for (int nb = 0; nb < 2; ++nb)
#pragma unroll
      for (int j = 0; j < 16; ++j) {
        int row = m0 + mb * 32 + 4 * lh + (j & 3) + 8 * (j >> 2);
        int col = n0 + nb * 32 + lr;
        out[(size_t)row * 1024 + col] = acc[mb][nb][j] * INV_WSCALE;
      }
}

extern "C" void kernel_launch(void* const* d_in, const int* in_sizes, int n_in,
                              void* d_out, int out_size, void* d_ws, size_t ws_size,
                              hipStream_t stream) {
  const float* x  = (const float*)d_in[0];
  const float* cc = (const float*)d_in[1];
  f16*   wt  = (f16*)d_ws;                        // 18,874,368 B
  f16*   t2  = (f16*)((char*)d_ws + 18874368);    // 33,554,432 B
  float* out = (float*)d_out;

  hipLaunchKernelGGL(wt_transform, dim3(1024), dim3(256), 0, stream, cc, wt);
  if (ws_size >= 52428800) {
    hipLaunchKernelGGL(t2_transform, dim3(8192), dim3(256), 0, stream, x, t2);
    hipLaunchKernelGGL(cheby_gemm, dim3(1024), dim3(256), 0, stream, t2, wt, out);
  } else {
    hipLaunchKernelGGL(cheby_gemm_fb, dim3(512), dim3(512), 0, stream, x, wt, out);
  }
}